// Round 2
// baseline (9029.128 us; speedup 1.0000x reference)
//
#include <hip/hip_runtime.h>

#define N_NODES 100000
#define N_EDGES 3200000
#define N_GRAPHS 64
#define NUM_CLASSES 40
#define DEG_BINS 512

// ---------------- CSR build ----------------

__global__ void hist_kernel(const int* __restrict__ dst, int* __restrict__ cnt, int n_edges) {
    int idx = blockIdx.x * blockDim.x + threadIdx.x;
    int stride = gridDim.x * blockDim.x;
    for (int e = idx; e < n_edges; e += stride)
        atomicAdd(&cnt[dst[e]], 1);
}

// Single-block exclusive scan over node counts. Writes row_start[0..N] and
// cursor[0..N-1] (= row_start copy, consumed by scatter). In-place over cnt.
__global__ __launch_bounds__(1024) void scan_kernel(int* __restrict__ cnt_cursor,
                                                    int* __restrict__ row_start,
                                                    int n_nodes) {
    const int T = 1024;
    int t = threadIdx.x;
    int chunk = (n_nodes + T - 1) / T;
    int s = t * chunk;
    int e = min(s + chunk, n_nodes);
    int sum = 0;
    for (int i = s; i < e; ++i) sum += cnt_cursor[i];
    __shared__ int tmp[T];
    tmp[t] = sum;
    __syncthreads();
    for (int off = 1; off < T; off <<= 1) {
        int v = (t >= off) ? tmp[t - off] : 0;
        __syncthreads();
        tmp[t] += v;
        __syncthreads();
    }
    int run = tmp[t] - sum;  // exclusive prefix
    for (int i = s; i < e; ++i) {
        int c = cnt_cursor[i];
        row_start[i] = run;
        cnt_cursor[i] = run;
        run += c;
    }
    if (t == T - 1) row_start[n_nodes] = run;  // == n_edges
}

__global__ void scatter_kernel(const int* __restrict__ src, const int* __restrict__ dst,
                               int* __restrict__ cursor, int* __restrict__ col, int n_edges) {
    int idx = blockIdx.x * blockDim.x + threadIdx.x;
    int stride = gridDim.x * blockDim.x;
    for (int e = idx; e < n_edges; e += stride) {
        int p = atomicAdd(&cursor[dst[e]], 1);
        col[p] = src[e];
    }
}

// ---------------- Degree-sort permutation (wave load balance) ----------------

__global__ void deg_hist_kernel(const int* __restrict__ row_start, int* __restrict__ dhist,
                                int n_nodes) {
    int n = blockIdx.x * blockDim.x + threadIdx.x;
    if (n >= n_nodes) return;
    int d = row_start[n + 1] - row_start[n];
    atomicAdd(&dhist[min(d, DEG_BINS - 1)], 1);
}

__global__ __launch_bounds__(DEG_BINS) void deg_scan_kernel(const int* __restrict__ dhist,
                                                            int* __restrict__ dcur) {
    __shared__ int tmp[DEG_BINS];
    int t = threadIdx.x;
    int v = dhist[t];
    tmp[t] = v;
    __syncthreads();
    for (int off = 1; off < DEG_BINS; off <<= 1) {
        int u = (t >= off) ? tmp[t - off] : 0;
        __syncthreads();
        tmp[t] += u;
        __syncthreads();
    }
    dcur[t] = tmp[t] - v;  // exclusive
}

__global__ void deg_perm_kernel(const int* __restrict__ row_start, int* __restrict__ dcur,
                                int* __restrict__ perm, int n_nodes) {
    int n = blockIdx.x * blockDim.x + threadIdx.x;
    if (n >= n_nodes) return;
    int d = row_start[n + 1] - row_start[n];
    int p = atomicAdd(&dcur[min(d, DEG_BINS - 1)], 1);
    perm[p] = n;
}

// ---------------- Per-node P/Q precompute ----------------

// Layer A: h = pos (3 dims). P = pos@(W1[0:3]+W1[3:6]); Q = pos@W1[3:6] - b1.
__global__ void pqa_kernel(const float* __restrict__ pos, const float* __restrict__ w1a,
                           const float* __restrict__ b1a,
                           float* __restrict__ P, float* __restrict__ Q, int n_nodes) {
    __shared__ float wtop[3][32], wbot[3][32], sb1[32];
    int t = threadIdx.x;
    if (t < 32) {
        for (int c = 0; c < 3; ++c) {
            wtop[c][t] = w1a[c * 32 + t];
            wbot[c][t] = w1a[(3 + c) * 32 + t];
        }
        sb1[t] = b1a[t];
    }
    __syncthreads();
    int n = blockIdx.x * blockDim.x + t;
    if (n >= n_nodes) return;
    float px = pos[n * 3 + 0], py = pos[n * 3 + 1], pz = pos[n * 3 + 2];
    float pv[32], qv[32];
#pragma unroll
    for (int k = 0; k < 32; ++k) {
        float wb = fmaf(px, wbot[0][k], fmaf(py, wbot[1][k], pz * wbot[2][k]));
        float wt = fmaf(px, wtop[0][k], fmaf(py, wtop[1][k], pz * wtop[2][k]));
        pv[k] = wt + wb;
        qv[k] = wb - sb1[k];
    }
    float4* Pp = (float4*)(P + (size_t)n * 32);
    float4* Qp = (float4*)(Q + (size_t)n * 32);
#pragma unroll
    for (int k = 0; k < 8; ++k) {
        Pp[k] = *(float4*)&pv[k * 4];
        Qp[k] = *(float4*)&qv[k * 4];
    }
}

// Layer B: P = h@W1[0:32] + pos@W1[32:35]; Q = pos@W1[32:35] - b1.
__global__ __launch_bounds__(256) void pqb_kernel(const float* __restrict__ pos,
                                                  const float* __restrict__ H,
                                                  const float* __restrict__ w1b,
                                                  const float* __restrict__ b1b,
                                                  float* __restrict__ P, float* __restrict__ Q,
                                                  int n_nodes) {
    __shared__ float sw[35 * 32];
    __shared__ float sb1[32];
    for (int i = threadIdx.x; i < 35 * 32; i += blockDim.x) sw[i] = w1b[i];
    if (threadIdx.x < 32) sb1[threadIdx.x] = b1b[threadIdx.x];
    __syncthreads();
    int n = blockIdx.x * blockDim.x + threadIdx.x;
    if (n >= n_nodes) return;
    float h[32];
    const float4* Hp = (const float4*)(H + (size_t)n * 32);
#pragma unroll
    for (int k = 0; k < 8; ++k) *(float4*)&h[k * 4] = Hp[k];
    float px = pos[n * 3 + 0], py = pos[n * 3 + 1], pz = pos[n * 3 + 2];
    float pv[32], qv[32];
#pragma unroll
    for (int k = 0; k < 32; ++k) {
        float pd = fmaf(px, sw[32 * 32 + k], fmaf(py, sw[33 * 32 + k], pz * sw[34 * 32 + k]));
        float hd = 0.f;
#pragma unroll
        for (int c = 0; c < 32; ++c) hd = fmaf(h[c], sw[c * 32 + k], hd);
        pv[k] = hd + pd;
        qv[k] = pd - sb1[k];
    }
    float4* Pp = (float4*)(P + (size_t)n * 32);
    float4* Qp = (float4*)(Q + (size_t)n * 32);
#pragma unroll
    for (int k = 0; k < 8; ++k) {
        Pp[k] = *(float4*)&pv[k * 4];
        Qp[k] = *(float4*)&qv[k * 4];
    }
}

// ---------------- Node-centric edge MLP + scatter-max ----------------
// One thread per destination node (via degree-sorted perm for wave balance).
// H[n] = max(0, b2 + max_e relu(P[src_e]-Q[n]) @ W2); empty nodes -> 0.
__global__ __launch_bounds__(256) void edge_kernel(const int* __restrict__ perm,
                                                   const int* __restrict__ row_start,
                                                   const int* __restrict__ col,
                                                   const float* __restrict__ P,
                                                   const float* __restrict__ Q,
                                                   const float* __restrict__ w2,
                                                   const float* __restrict__ b2,
                                                   float* __restrict__ H, int n_nodes) {
    __shared__ float sw2[32 * 32];
    __shared__ float sb2[32];
    for (int i = threadIdx.x; i < 32 * 32; i += blockDim.x) sw2[i] = w2[i];
    if (threadIdx.x < 32) sb2[threadIdx.x] = b2[threadIdx.x];
    __syncthreads();
    int idx = blockIdx.x * blockDim.x + threadIdx.x;
    if (idx >= n_nodes) return;
    int n = perm[idx];

    float q[32];
    const float4* Qp = (const float4*)(Q + (size_t)n * 32);
#pragma unroll
    for (int k = 0; k < 8; ++k) *(float4*)&q[k * 4] = Qp[k];

    float acc[32];
#pragma unroll
    for (int j = 0; j < 32; ++j) acc[j] = -3.0e38f;  // bias hoisted; empty -> 0 at end

    int e0 = row_start[n], e1 = row_start[n + 1];
    for (int e = e0; e < e1; ++e) {
        int jn = col[e];
        float p[32];
        const float4* Pp = (const float4*)(P + (size_t)jn * 32);
#pragma unroll
        for (int k = 0; k < 8; ++k) *(float4*)&p[k * 4] = Pp[k];
        float m[32];
        float x0 = fmaxf(p[0] - q[0], 0.f);
#pragma unroll
        for (int j = 0; j < 32; ++j) m[j] = x0 * sw2[j];
#pragma unroll
        for (int k = 1; k < 32; ++k) {
            float xk = fmaxf(p[k] - q[k], 0.f);
#pragma unroll
            for (int j = 0; j < 32; ++j) m[j] = fmaf(xk, sw2[k * 32 + j], m[j]);
        }
#pragma unroll
        for (int j = 0; j < 32; ++j) acc[j] = fmaxf(acc[j], m[j]);
    }
    float out[32];
#pragma unroll
    for (int j = 0; j < 32; ++j) out[j] = fmaxf(acc[j] + sb2[j], 0.f);
    float4* Hp = (float4*)(H + (size_t)n * 32);
#pragma unroll
    for (int k = 0; k < 8; ++k) Hp[k] = *(float4*)&out[k * 4];
}

// ---------------- Global max pool (batch is sorted) ----------------
__global__ __launch_bounds__(256) void pool_kernel(const float* __restrict__ H,
                                                   const int* __restrict__ batch,
                                                   float* __restrict__ gmax, int n_nodes) {
    int g = blockIdx.x;
    int lo = 0, hi = n_nodes;
    while (lo < hi) { int mid = (lo + hi) >> 1; if (batch[mid] < g) lo = mid + 1; else hi = mid; }
    int s = lo;
    lo = 0; hi = n_nodes;
    while (lo < hi) { int mid = (lo + hi) >> 1; if (batch[mid] < g + 1) lo = mid + 1; else hi = mid; }
    int e = lo;

    float acc[32];
#pragma unroll
    for (int c = 0; c < 32; ++c) acc[c] = 0.f;  // H >= 0; empty graphs -> 0
    for (int n = s + threadIdx.x; n < e; n += blockDim.x) {
        const float4* Hp = (const float4*)(H + (size_t)n * 32);
#pragma unroll
        for (int k = 0; k < 8; ++k) {
            float4 v = Hp[k];
            acc[k * 4 + 0] = fmaxf(acc[k * 4 + 0], v.x);
            acc[k * 4 + 1] = fmaxf(acc[k * 4 + 1], v.y);
            acc[k * 4 + 2] = fmaxf(acc[k * 4 + 2], v.z);
            acc[k * 4 + 3] = fmaxf(acc[k * 4 + 3], v.w);
        }
    }
#pragma unroll
    for (int off = 32; off >= 1; off >>= 1)
#pragma unroll
        for (int c = 0; c < 32; ++c) acc[c] = fmaxf(acc[c], __shfl_xor(acc[c], off));
    __shared__ float red[4][32];
    int wid = threadIdx.x >> 6, lane = threadIdx.x & 63;
    if (lane == 0)
#pragma unroll
        for (int c = 0; c < 32; ++c) red[wid][c] = acc[c];
    __syncthreads();
    if (threadIdx.x < 32) {
        int c = threadIdx.x;
        float v = fmaxf(fmaxf(red[0][c], red[1][c]), fmaxf(red[2][c], red[3][c]));
        gmax[g * 32 + c] = v;
    }
}

__global__ void classifier_kernel(const float* __restrict__ gmax, const float* __restrict__ wc,
                                  const float* __restrict__ bc, float* __restrict__ out) {
    int idx = blockIdx.x * blockDim.x + threadIdx.x;
    if (idx >= N_GRAPHS * NUM_CLASSES) return;
    int g = idx / NUM_CLASSES, c = idx % NUM_CLASSES;
    float v = bc[c];
#pragma unroll
    for (int k = 0; k < 32; ++k) v = fmaf(gmax[g * 32 + k], wc[k * NUM_CLASSES + c], v);
    out[idx] = v;
}

// ---------------- Launch ----------------

extern "C" void kernel_launch(void* const* d_in, const int* in_sizes, int n_in,
                              void* d_out, int out_size, void* d_ws, size_t ws_size,
                              hipStream_t stream) {
    const float* pos = (const float*)d_in[0];
    const int* ei = (const int*)d_in[1];
    const int* batch = (const int*)d_in[2];
    const float* w1a = (const float*)d_in[3];
    const float* b1a = (const float*)d_in[4];
    const float* w2a = (const float*)d_in[5];
    const float* b2a = (const float*)d_in[6];
    const float* w1b = (const float*)d_in[7];
    const float* b1b = (const float*)d_in[8];
    const float* w2b = (const float*)d_in[9];
    const float* b2b = (const float*)d_in[10];
    const float* wc = (const float*)d_in[11];
    const float* bc = (const float*)d_in[12];
    float* out = (float*)d_out;

    // workspace layout (~53 MB)
    float* Pbuf = (float*)d_ws;                             // N*32 f32
    float* Qbuf = Pbuf + (size_t)N_NODES * 32;              // N*32 f32
    float* Hbuf = Qbuf + (size_t)N_NODES * 32;              // N*32 f32
    int* row_start = (int*)(Hbuf + (size_t)N_NODES * 32);   // N+1
    int* cursor = row_start + (N_NODES + 1);                // N (also dst histogram)
    int* col = cursor + N_NODES;                            // E
    int* perm = col + N_EDGES;                              // N
    int* dhist = perm + N_NODES;                            // DEG_BINS
    int* dcur = dhist + DEG_BINS;                           // DEG_BINS
    float* gmax = (float*)(dcur + DEG_BINS);                // 64*32

    const int* srcv = ei;
    const int* dstv = ei + N_EDGES;

    hipMemsetAsync(cursor, 0, N_NODES * sizeof(int), stream);
    hipMemsetAsync(dhist, 0, DEG_BINS * sizeof(int), stream);
    hist_kernel<<<2048, 256, 0, stream>>>(dstv, cursor, N_EDGES);
    scan_kernel<<<1, 1024, 0, stream>>>(cursor, row_start, N_NODES);
    scatter_kernel<<<2048, 256, 0, stream>>>(srcv, dstv, cursor, col, N_EDGES);

    int nblk = (N_NODES + 255) / 256;
    deg_hist_kernel<<<nblk, 256, 0, stream>>>(row_start, dhist, N_NODES);
    deg_scan_kernel<<<1, DEG_BINS, 0, stream>>>(dhist, dcur);
    deg_perm_kernel<<<nblk, 256, 0, stream>>>(row_start, dcur, perm, N_NODES);

    pqa_kernel<<<nblk, 256, 0, stream>>>(pos, w1a, b1a, Pbuf, Qbuf, N_NODES);
    edge_kernel<<<nblk, 256, 0, stream>>>(perm, row_start, col, Pbuf, Qbuf, w2a, b2a, Hbuf, N_NODES);
    pqb_kernel<<<nblk, 256, 0, stream>>>(pos, Hbuf, w1b, b1b, Pbuf, Qbuf, N_NODES);
    edge_kernel<<<nblk, 256, 0, stream>>>(perm, row_start, col, Pbuf, Qbuf, w2b, b2b, Hbuf, N_NODES);

    pool_kernel<<<N_GRAPHS, 256, 0, stream>>>(Hbuf, batch, gmax, N_NODES);
    classifier_kernel<<<(N_GRAPHS * NUM_CLASSES + 255) / 256, 256, 0, stream>>>(gmax, wc, bc, out);
}

// Round 6
// 2649.854 us; speedup vs baseline: 3.4074x; 3.4074x over previous
//
#include <hip/hip_runtime.h>

#define N_NODES 100000
#define N_EDGES 3200000
#define N_GRAPHS 64
#define NUM_CLASSES 40
#define DEG_BINS 512

// ---------------- CSR build ----------------

__global__ void hist_kernel(const int* __restrict__ dst, int* __restrict__ cnt, int n_edges) {
    int idx = blockIdx.x * blockDim.x + threadIdx.x;
    int stride = gridDim.x * blockDim.x;
    for (int e = idx; e < n_edges; e += stride)
        atomicAdd(&cnt[dst[e]], 1);
}

// Single-block exclusive scan over node counts. Writes row_start[0..N] and
// cursor copy (consumed by scatter). In-place over cnt.
__global__ __launch_bounds__(1024) void scan_kernel(int* __restrict__ cnt_cursor,
                                                    int* __restrict__ row_start,
                                                    int n_nodes) {
    const int T = 1024;
    int t = threadIdx.x;
    int chunk = (n_nodes + T - 1) / T;
    int s = t * chunk;
    int e = min(s + chunk, n_nodes);
    int sum = 0;
    for (int i = s; i < e; ++i) sum += cnt_cursor[i];
    __shared__ int tmp[T];
    tmp[t] = sum;
    __syncthreads();
    for (int off = 1; off < T; off <<= 1) {
        int v = (t >= off) ? tmp[t - off] : 0;
        __syncthreads();
        tmp[t] += v;
        __syncthreads();
    }
    int run = tmp[t] - sum;  // exclusive prefix
    for (int i = s; i < e; ++i) {
        int c = cnt_cursor[i];
        row_start[i] = run;
        cnt_cursor[i] = run;
        run += c;
    }
    if (t == T - 1) row_start[n_nodes] = run;  // == n_edges
}

__global__ void scatter_kernel(const int* __restrict__ src, const int* __restrict__ dst,
                               int* __restrict__ cursor, int* __restrict__ col, int n_edges) {
    int idx = blockIdx.x * blockDim.x + threadIdx.x;
    int stride = gridDim.x * blockDim.x;
    for (int e = idx; e < n_edges; e += stride) {
        int p = atomicAdd(&cursor[dst[e]], 1);
        col[p] = src[e];
    }
}

// ---------------- Degree-sort permutation (wave load balance) ----------------

__global__ void deg_hist_kernel(const int* __restrict__ row_start, int* __restrict__ dhist,
                                int n_nodes) {
    int n = blockIdx.x * blockDim.x + threadIdx.x;
    if (n >= n_nodes) return;
    int d = row_start[n + 1] - row_start[n];
    atomicAdd(&dhist[min(d, DEG_BINS - 1)], 1);
}

__global__ __launch_bounds__(DEG_BINS) void deg_scan_kernel(const int* __restrict__ dhist,
                                                            int* __restrict__ dcur) {
    __shared__ int tmp[DEG_BINS];
    int t = threadIdx.x;
    int v = dhist[t];
    tmp[t] = v;
    __syncthreads();
    for (int off = 1; off < DEG_BINS; off <<= 1) {
        int u = (t >= off) ? tmp[t - off] : 0;
        __syncthreads();
        tmp[t] += u;
        __syncthreads();
    }
    dcur[t] = tmp[t] - v;  // exclusive
}

__global__ void deg_perm_kernel(const int* __restrict__ row_start, int* __restrict__ dcur,
                                int* __restrict__ perm, int n_nodes) {
    int n = blockIdx.x * blockDim.x + threadIdx.x;
    if (n >= n_nodes) return;
    int d = row_start[n + 1] - row_start[n];
    int p = atomicAdd(&dcur[min(d, DEG_BINS - 1)], 1);
    perm[p] = n;
}

// ---------------- Per-node P/Q precompute ----------------

// Layer A: h = pos (3 dims). P = pos@(W1[0:3]+W1[3:6]); Q = pos@W1[3:6] - b1.
__global__ void pqa_kernel(const float* __restrict__ pos, const float* __restrict__ w1a,
                           const float* __restrict__ b1a,
                           float* __restrict__ P, float* __restrict__ Q, int n_nodes) {
    __shared__ float wtop[3][32], wbot[3][32], sb1[32];
    int t = threadIdx.x;
    if (t < 32) {
        for (int c = 0; c < 3; ++c) {
            wtop[c][t] = w1a[c * 32 + t];
            wbot[c][t] = w1a[(3 + c) * 32 + t];
        }
        sb1[t] = b1a[t];
    }
    __syncthreads();
    int n = blockIdx.x * blockDim.x + t;
    if (n >= n_nodes) return;
    float px = pos[n * 3 + 0], py = pos[n * 3 + 1], pz = pos[n * 3 + 2];
    float pv[32], qv[32];
#pragma unroll
    for (int k = 0; k < 32; ++k) {
        float wb = fmaf(px, wbot[0][k], fmaf(py, wbot[1][k], pz * wbot[2][k]));
        float wt = fmaf(px, wtop[0][k], fmaf(py, wtop[1][k], pz * wtop[2][k]));
        pv[k] = wt + wb;
        qv[k] = wb - sb1[k];
    }
    float4* Pp = (float4*)(P + (size_t)n * 32);
    float4* Qp = (float4*)(Q + (size_t)n * 32);
#pragma unroll
    for (int k = 0; k < 8; ++k) {
        Pp[k] = *(float4*)&pv[k * 4];
        Qp[k] = *(float4*)&qv[k * 4];
    }
}

// Layer B: P = h@W1[0:32] + pos@W1[32:35]; Q = pos@W1[32:35] - b1.
__global__ __launch_bounds__(256) void pqb_kernel(const float* __restrict__ pos,
                                                  const float* __restrict__ H,
                                                  const float* __restrict__ w1b,
                                                  const float* __restrict__ b1b,
                                                  float* __restrict__ P, float* __restrict__ Q,
                                                  int n_nodes) {
    __shared__ float sw[35 * 32];
    __shared__ float sb1[32];
    for (int i = threadIdx.x; i < 35 * 32; i += blockDim.x) sw[i] = w1b[i];
    if (threadIdx.x < 32) sb1[threadIdx.x] = b1b[threadIdx.x];
    __syncthreads();
    int n = blockIdx.x * blockDim.x + threadIdx.x;
    if (n >= n_nodes) return;
    float h[32];
    const float4* Hp = (const float4*)(H + (size_t)n * 32);
#pragma unroll
    for (int k = 0; k < 8; ++k) *(float4*)&h[k * 4] = Hp[k];
    float px = pos[n * 3 + 0], py = pos[n * 3 + 1], pz = pos[n * 3 + 2];
    float pv[32], qv[32];
#pragma unroll
    for (int k = 0; k < 32; ++k) {
        float pd = fmaf(px, sw[32 * 32 + k], fmaf(py, sw[33 * 32 + k], pz * sw[34 * 32 + k]));
        float hd = 0.f;
#pragma unroll
        for (int c = 0; c < 32; ++c) hd = fmaf(h[c], sw[c * 32 + k], hd);
        pv[k] = hd + pd;
        qv[k] = pd - sb1[k];
    }
    float4* Pp = (float4*)(P + (size_t)n * 32);
    float4* Qp = (float4*)(Q + (size_t)n * 32);
#pragma unroll
    for (int k = 0; k < 8; ++k) {
        Pp[k] = *(float4*)&pv[k * 4];
        Qp[k] = *(float4*)&qv[k * 4];
    }
}

// ---------------- Node-centric edge MLP + scatter-max ----------------
// 4 lanes per destination node. Lane c owns output channels [8c,8c+8) and
// loads k-chunk [8c,8c+8) of P/Q rows (coalesced 128B per quad). 4-edge
// unroll shares each W2 LDS row read across 4 edges; x_k broadcast within
// the quad via DPP quad_perm (VALU pipe, not LDS). Odd tails: duplicate the
// last edge (max is idempotent).
// H[n] = max(0, b2 + max_e relu(P[src_e]-Q[n]) @ W2); empty nodes -> 0.

template <int S>
__device__ __forceinline__ float qb(float v) {
#if __has_builtin(__builtin_amdgcn_update_dpp)
    // quad_perm [S,S,S,S]: broadcast lane S of each quad. VALU op.
    int iv = __float_as_int(v);
    return __int_as_float(
        __builtin_amdgcn_update_dpp(iv, iv, S * 0x55, 0xf, 0xf, false));
#else
    return __shfl(v, S, 4);
#endif
}

#define KBLOCK(S, FIRST)                                                       \
    _Pragma("unroll") for (int r = 0; r < 8; ++r) {                            \
        float wv[8];                                                           \
        const float* wr = sw2 + (S * 8 + r) * 32 + c8;                         \
        *(float4*)&wv[0] = *(const float4*)(wr);                               \
        *(float4*)&wv[4] = *(const float4*)(wr + 4);                           \
        float ya = qb<S>(xa[r]);                                               \
        float yb = qb<S>(xb[r]);                                               \
        float yc = qb<S>(xc[r]);                                               \
        float yd = qb<S>(xd[r]);                                               \
        if (FIRST && r == 0) {                                                 \
            _Pragma("unroll") for (int jl = 0; jl < 8; ++jl) {                 \
                ma[jl] = ya * wv[jl];                                          \
                mb[jl] = yb * wv[jl];                                          \
                mc[jl] = yc * wv[jl];                                          \
                md[jl] = yd * wv[jl];                                          \
            }                                                                  \
        } else {                                                               \
            _Pragma("unroll") for (int jl = 0; jl < 8; ++jl) {                 \
                ma[jl] = fmaf(ya, wv[jl], ma[jl]);                             \
                mb[jl] = fmaf(yb, wv[jl], mb[jl]);                             \
                mc[jl] = fmaf(yc, wv[jl], mc[jl]);                             \
                md[jl] = fmaf(yd, wv[jl], md[jl]);                             \
            }                                                                  \
        }                                                                      \
    }

__global__ __launch_bounds__(256, 4) void edge_kernel(const int* __restrict__ perm,
                                                      const int* __restrict__ row_start,
                                                      const int* __restrict__ col,
                                                      const float* __restrict__ P,
                                                      const float* __restrict__ Q,
                                                      const float* __restrict__ w2,
                                                      const float* __restrict__ b2,
                                                      float* __restrict__ H, int n_nodes) {
    __shared__ float sw2[32 * 32];
    __shared__ float sb2[32];
    for (int i = threadIdx.x; i < 32 * 32; i += blockDim.x) sw2[i] = w2[i];
    if (threadIdx.x < 32) sb2[threadIdx.x] = b2[threadIdx.x];
    __syncthreads();
    int gid = (blockIdx.x * blockDim.x + threadIdx.x) >> 2;
    int c = threadIdx.x & 3;
    if (gid >= n_nodes) return;
    int n = perm[gid];
    int c8 = c * 8;

    float q[8];
    {
        const float4* Qp = (const float4*)(Q + (size_t)n * 32 + c8);
        *(float4*)&q[0] = Qp[0];
        *(float4*)&q[4] = Qp[1];
    }
    float acc[8];
#pragma unroll
    for (int j = 0; j < 8; ++j) acc[j] = -3.0e38f;  // bias hoisted; empty -> 0 at end

    int e0 = row_start[n], e1 = row_start[n + 1];
    for (int e = e0; e < e1; e += 4) {
        int el = e1 - 1;
        int ia = col[e];
        int ib = col[min(e + 1, el)];
        int ic = col[min(e + 2, el)];
        int id = col[min(e + 3, el)];
        float xa[8], xb[8], xc[8], xd[8];
        {
            const float4* Pa = (const float4*)(P + (size_t)ia * 32 + c8);
            const float4* Pb = (const float4*)(P + (size_t)ib * 32 + c8);
            const float4* Pc = (const float4*)(P + (size_t)ic * 32 + c8);
            const float4* Pd = (const float4*)(P + (size_t)id * 32 + c8);
            *(float4*)&xa[0] = Pa[0]; *(float4*)&xa[4] = Pa[1];
            *(float4*)&xb[0] = Pb[0]; *(float4*)&xb[4] = Pb[1];
            *(float4*)&xc[0] = Pc[0]; *(float4*)&xc[4] = Pc[1];
            *(float4*)&xd[0] = Pd[0]; *(float4*)&xd[4] = Pd[1];
        }
#pragma unroll
        for (int r = 0; r < 8; ++r) {
            xa[r] = fmaxf(xa[r] - q[r], 0.f);
            xb[r] = fmaxf(xb[r] - q[r], 0.f);
            xc[r] = fmaxf(xc[r] - q[r], 0.f);
            xd[r] = fmaxf(xd[r] - q[r], 0.f);
        }
        float ma[8], mb[8], mc[8], md[8];
        KBLOCK(0, true)
        KBLOCK(1, false)
        KBLOCK(2, false)
        KBLOCK(3, false)
#pragma unroll
        for (int jl = 0; jl < 8; ++jl)
            acc[jl] = fmaxf(acc[jl], fmaxf(fmaxf(ma[jl], mb[jl]), fmaxf(mc[jl], md[jl])));
    }
    float outv[8];
#pragma unroll
    for (int jl = 0; jl < 8; ++jl) outv[jl] = fmaxf(acc[jl] + sb2[c8 + jl], 0.f);
    float4* Hp = (float4*)(H + (size_t)n * 32 + c8);
    Hp[0] = *(float4*)&outv[0];
    Hp[1] = *(float4*)&outv[4];
}

// ---------------- Global max pool (batch is sorted) ----------------
__global__ __launch_bounds__(256) void pool_kernel(const float* __restrict__ H,
                                                   const int* __restrict__ batch,
                                                   float* __restrict__ gmax, int n_nodes) {
    int g = blockIdx.x;
    int lo = 0, hi = n_nodes;
    while (lo < hi) { int mid = (lo + hi) >> 1; if (batch[mid] < g) lo = mid + 1; else hi = mid; }
    int s = lo;
    lo = 0; hi = n_nodes;
    while (lo < hi) { int mid = (lo + hi) >> 1; if (batch[mid] < g + 1) lo = mid + 1; else hi = mid; }
    int e = lo;

    float acc[32];
#pragma unroll
    for (int ch = 0; ch < 32; ++ch) acc[ch] = 0.f;  // H >= 0; empty graphs -> 0
    for (int n = s + threadIdx.x; n < e; n += blockDim.x) {
        const float4* Hp = (const float4*)(H + (size_t)n * 32);
#pragma unroll
        for (int k = 0; k < 8; ++k) {
            float4 v = Hp[k];
            acc[k * 4 + 0] = fmaxf(acc[k * 4 + 0], v.x);
            acc[k * 4 + 1] = fmaxf(acc[k * 4 + 1], v.y);
            acc[k * 4 + 2] = fmaxf(acc[k * 4 + 2], v.z);
            acc[k * 4 + 3] = fmaxf(acc[k * 4 + 3], v.w);
        }
    }
#pragma unroll
    for (int off = 32; off >= 1; off >>= 1)
#pragma unroll
        for (int ch = 0; ch < 32; ++ch) acc[ch] = fmaxf(acc[ch], __shfl_xor(acc[ch], off));
    __shared__ float red[4][32];
    int wid = threadIdx.x >> 6, lane = threadIdx.x & 63;
    if (lane == 0)
#pragma unroll
        for (int ch = 0; ch < 32; ++ch) red[wid][ch] = acc[ch];
    __syncthreads();
    if (threadIdx.x < 32) {
        int ch = threadIdx.x;
        float v = fmaxf(fmaxf(red[0][ch], red[1][ch]), fmaxf(red[2][ch], red[3][ch]));
        gmax[g * 32 + ch] = v;
    }
}

__global__ void classifier_kernel(const float* __restrict__ gmax, const float* __restrict__ wc,
                                  const float* __restrict__ bc, float* __restrict__ out) {
    int idx = blockIdx.x * blockDim.x + threadIdx.x;
    if (idx >= N_GRAPHS * NUM_CLASSES) return;
    int g = idx / NUM_CLASSES, c = idx % NUM_CLASSES;
    float v = bc[c];
#pragma unroll
    for (int k = 0; k < 32; ++k) v = fmaf(gmax[g * 32 + k], wc[k * NUM_CLASSES + c], v);
    out[idx] = v;
}

// ---------------- Launch ----------------

extern "C" void kernel_launch(void* const* d_in, const int* in_sizes, int n_in,
                              void* d_out, int out_size, void* d_ws, size_t ws_size,
                              hipStream_t stream) {
    const float* pos = (const float*)d_in[0];
    const int* ei = (const int*)d_in[1];
    const int* batch = (const int*)d_in[2];
    const float* w1a = (const float*)d_in[3];
    const float* b1a = (const float*)d_in[4];
    const float* w2a = (const float*)d_in[5];
    const float* b2a = (const float*)d_in[6];
    const float* w1b = (const float*)d_in[7];
    const float* b1b = (const float*)d_in[8];
    const float* w2b = (const float*)d_in[9];
    const float* b2b = (const float*)d_in[10];
    const float* wc = (const float*)d_in[11];
    const float* bc = (const float*)d_in[12];
    float* out = (float*)d_out;

    // workspace layout (~53 MB)
    float* Pbuf = (float*)d_ws;                             // N*32 f32
    float* Qbuf = Pbuf + (size_t)N_NODES * 32;              // N*32 f32
    float* Hbuf = Qbuf + (size_t)N_NODES * 32;              // N*32 f32
    int* row_start = (int*)(Hbuf + (size_t)N_NODES * 32);   // N+1
    int* cursor = row_start + (N_NODES + 1);                // N (also dst histogram)
    int* col = cursor + N_NODES;                            // E
    int* perm = col + N_EDGES;                              // N
    int* dhist = perm + N_NODES;                            // DEG_BINS
    int* dcur = dhist + DEG_BINS;                           // DEG_BINS
    float* gmax = (float*)(dcur + DEG_BINS);                // 64*32

    const int* srcv = ei;
    const int* dstv = ei + N_EDGES;

    hipMemsetAsync(cursor, 0, N_NODES * sizeof(int), stream);
    hipMemsetAsync(dhist, 0, DEG_BINS * sizeof(int), stream);
    hist_kernel<<<2048, 256, 0, stream>>>(dstv, cursor, N_EDGES);
    scan_kernel<<<1, 1024, 0, stream>>>(cursor, row_start, N_NODES);
    scatter_kernel<<<2048, 256, 0, stream>>>(srcv, dstv, cursor, col, N_EDGES);

    int nblk = (N_NODES + 255) / 256;
    deg_hist_kernel<<<nblk, 256, 0, stream>>>(row_start, dhist, N_NODES);
    deg_scan_kernel<<<1, DEG_BINS, 0, stream>>>(dhist, dcur);
    deg_perm_kernel<<<nblk, 256, 0, stream>>>(row_start, dcur, perm, N_NODES);

    int eblk = ((N_NODES * 4) + 255) / 256;
    pqa_kernel<<<nblk, 256, 0, stream>>>(pos, w1a, b1a, Pbuf, Qbuf, N_NODES);
    edge_kernel<<<eblk, 256, 0, stream>>>(perm, row_start, col, Pbuf, Qbuf, w2a, b2a, Hbuf, N_NODES);
    pqb_kernel<<<nblk, 256, 0, stream>>>(pos, Hbuf, w1b, b1b, Pbuf, Qbuf, N_NODES);
    edge_kernel<<<eblk, 256, 0, stream>>>(perm, row_start, col, Pbuf, Qbuf, w2b, b2b, Hbuf, N_NODES);

    pool_kernel<<<N_GRAPHS, 256, 0, stream>>>(Hbuf, batch, gmax, N_NODES);
    classifier_kernel<<<(N_GRAPHS * NUM_CLASSES + 255) / 256, 256, 0, stream>>>(gmax, wc, bc, out);
}